// Round 1
// baseline (1132.438 us; speedup 1.0000x reference)
//
#include <hip/hip_runtime.h>

#define N_NODES 80000
#define N_EDGES 1280000
#define D 64          // D_IN == D_OUT == 64

// ---------------------------------------------------------------------------
// Kernel 1: support = X @ W   (one thread per row; W staged in LDS)
// ---------------------------------------------------------------------------
__global__ __launch_bounds__(256) void gemm_xw(const float* __restrict__ x,
                                               const float* __restrict__ w,
                                               float* __restrict__ support) {
    __shared__ float4 Ws[D * 16];      // [k][j4] : 64 x 16 float4 = 16 KB
    const int tid = threadIdx.x;
    // cooperative load of W (1024 float4s, 256 threads -> 4 each)
    for (int i = tid; i < D * 16; i += 256) {
        Ws[i] = ((const float4*)w)[i];
    }
    __syncthreads();

    const int row = blockIdx.x * 256 + tid;
    if (row >= N_NODES) return;

    const float4* xr = (const float4*)(x + (size_t)row * D);
    float4 acc[16];
#pragma unroll
    for (int j = 0; j < 16; ++j) acc[j] = make_float4(0.f, 0.f, 0.f, 0.f);

    for (int k4 = 0; k4 < 16; ++k4) {
        const float4 xv = xr[k4];
        const float xs[4] = {xv.x, xv.y, xv.z, xv.w};
#pragma unroll
        for (int kk = 0; kk < 4; ++kk) {
            const float xk = xs[kk];
            const int k = k4 * 4 + kk;
#pragma unroll
            for (int j = 0; j < 16; ++j) {
                const float4 wv = Ws[k * 16 + j];   // uniform addr -> broadcast
                acc[j].x += xk * wv.x;
                acc[j].y += xk * wv.y;
                acc[j].z += xk * wv.z;
                acc[j].w += xk * wv.w;
            }
        }
    }

    float4* outr = (float4*)(support + (size_t)row * D);
#pragma unroll
    for (int j = 0; j < 16; ++j) outr[j] = acc[j];
}

// ---------------------------------------------------------------------------
// Kernel 2: out[i, :] = bias   (so the scatter accumulates bias-included)
// ---------------------------------------------------------------------------
__global__ __launch_bounds__(256) void init_out(const float* __restrict__ bias,
                                                float* __restrict__ out) {
    __shared__ float4 b4[16];
    if (threadIdx.x < 16) b4[threadIdx.x] = ((const float4*)bias)[threadIdx.x];
    __syncthreads();
    const int idx = blockIdx.x * 256 + threadIdx.x;      // float4 index
    const int total = N_NODES * 16;
    if (idx < total) {
        ((float4*)out)[idx] = b4[idx & 15];
    }
}

// ---------------------------------------------------------------------------
// Kernel 3: per-edge gather + scale + atomic scatter
//   16 threads per edge, each does one float4 (256 B / edge, coalesced)
// ---------------------------------------------------------------------------
__global__ __launch_bounds__(256) void scatter_edges(const int* __restrict__ ei,
                                                     const float* __restrict__ ew,
                                                     const float* __restrict__ support,
                                                     float* __restrict__ out) {
    const long tid = (long)blockIdx.x * 256 + threadIdx.x;
    const int e = (int)(tid >> 4);
    const int l = (int)(tid & 15);
    if (e >= N_EDGES) return;

    const int src = ei[e];
    const int dst = ei[N_EDGES + e];
    const float wt = ew[e];

    const float4 v = ((const float4*)(support + (size_t)src * D))[l];
    float* o = out + (size_t)dst * D + l * 4;
    atomicAdd(o + 0, v.x * wt);
    atomicAdd(o + 1, v.y * wt);
    atomicAdd(o + 2, v.z * wt);
    atomicAdd(o + 3, v.w * wt);
}

// ---------------------------------------------------------------------------
extern "C" void kernel_launch(void* const* d_in, const int* in_sizes, int n_in,
                              void* d_out, int out_size, void* d_ws, size_t ws_size,
                              hipStream_t stream) {
    const float* x      = (const float*)d_in[0];   // [N_NODES, D]
    const int*   ei     = (const int*)d_in[1];     // [2, N_EDGES]
    const float* ew     = (const float*)d_in[2];   // [N_EDGES]
    const float* weight = (const float*)d_in[3];   // [D, D]
    const float* bias   = (const float*)d_in[4];   // [D]
    float* out = (float*)d_out;                    // [N_NODES, D]
    float* support = (float*)d_ws;                 // [N_NODES, D] scratch

    // 1. support = X @ W
    {
        const int blocks = (N_NODES + 255) / 256;
        gemm_xw<<<blocks, 256, 0, stream>>>(x, weight, support);
    }
    // 2. out = bias (broadcast)
    {
        const int total = N_NODES * 16;            // float4 count
        const int blocks = (total + 255) / 256;
        init_out<<<blocks, 256, 0, stream>>>(bias, out);
    }
    // 3. out += A * support (atomic scatter)
    {
        const long total = (long)N_EDGES * 16;
        const int blocks = (int)((total + 255) / 256);
        scatter_edges<<<blocks, 256, 0, stream>>>(ei, ew, support, out);
    }
}

// Round 2
// 195.823 us; speedup vs baseline: 5.7830x; 5.7830x over previous
//
#include <hip/hip_runtime.h>

#define N_NODES 80000
#define N_EDGES 1280000
#define D 64          // D_IN == D_OUT == 64
#define CAP 32        // bucket capacity per node (Poisson(16) tail; overflow handled)

// ---------------- workspace layout (bytes, 256-aligned) ----------------
#define OFF_SUPPORT  0u
#define SUP_BYTES    (N_NODES * D * 4u)                 // 20,480,000
#define OFF_COUNTS   (OFF_SUPPORT + SUP_BYTES)          // 20,480,000
#define CNT_BYTES    (N_NODES * 4u)                     //    320,000
#define OFF_OVFCNT   (OFF_COUNTS + CNT_BYTES)           // 20,800,000
#define OVFCNT_BYTES 256u
#define OFF_BUCKETS  (OFF_OVFCNT + OVFCNT_BYTES)        // 20,800,256
#define BKT_BYTES    (N_NODES * CAP * 8u)               // 20,480,000
#define OFF_OVF      (OFF_BUCKETS + BKT_BYTES)          // 41,280,256
#define OVF_BYTES    (N_EDGES * 4u)                     //  5,120,000
#define WS_NEEDED    (OFF_OVF + OVF_BYTES)              // 46,400,256

// ---------------------------------------------------------------------------
// Kernel 1: support = X @ W   (one thread per row; W staged in LDS)
// ---------------------------------------------------------------------------
__global__ __launch_bounds__(256) void gemm_xw(const float* __restrict__ x,
                                               const float* __restrict__ w,
                                               float* __restrict__ support) {
    __shared__ float4 Ws[D * 16];      // [k][j4] : 64 x 16 float4 = 16 KB
    const int tid = threadIdx.x;
    for (int i = tid; i < D * 16; i += 256) {
        Ws[i] = ((const float4*)w)[i];
    }
    __syncthreads();

    const int row = blockIdx.x * 256 + tid;
    if (row >= N_NODES) return;

    const float4* xr = (const float4*)(x + (size_t)row * D);
    float4 acc[16];
#pragma unroll
    for (int j = 0; j < 16; ++j) acc[j] = make_float4(0.f, 0.f, 0.f, 0.f);

    for (int k4 = 0; k4 < 16; ++k4) {
        const float4 xv = xr[k4];
        const float xs[4] = {xv.x, xv.y, xv.z, xv.w};
#pragma unroll
        for (int kk = 0; kk < 4; ++kk) {
            const float xk = xs[kk];
            const int k = k4 * 4 + kk;
#pragma unroll
            for (int j = 0; j < 16; ++j) {
                const float4 wv = Ws[k * 16 + j];
                acc[j].x += xk * wv.x;
                acc[j].y += xk * wv.y;
                acc[j].z += xk * wv.z;
                acc[j].w += xk * wv.w;
            }
        }
    }

    float4* outr = (float4*)(support + (size_t)row * D);
#pragma unroll
    for (int j = 0; j < 16; ++j) outr[j] = acc[j];
}

// ---------------------------------------------------------------------------
// Kernel 2: bucket edges by dst.  slot via int atomic; (src, weight) -> int2.
// Overflow (slot >= CAP) edges appended to ovf_list for a cleanup pass.
// ---------------------------------------------------------------------------
__global__ __launch_bounds__(256) void fill_buckets(const int* __restrict__ ei,
                                                    const float* __restrict__ ew,
                                                    int* __restrict__ counts,
                                                    int2* __restrict__ buckets,
                                                    int* __restrict__ ovf_cnt,
                                                    int* __restrict__ ovf_list) {
    const int e = blockIdx.x * 256 + threadIdx.x;
    if (e >= N_EDGES) return;
    const int dst = ei[N_EDGES + e];
    const int slot = atomicAdd(&counts[dst], 1);
    if (slot < CAP) {
        buckets[(size_t)dst * CAP + slot] = make_int2(ei[e], __float_as_int(ew[e]));
    } else {
        const int p = atomicAdd(ovf_cnt, 1);
        ovf_list[p] = e;
    }
}

// ---------------------------------------------------------------------------
// Kernel 3: out[node,:] = bias + sum over bucket (16 lanes per node, float4)
// ---------------------------------------------------------------------------
__global__ __launch_bounds__(256) void gather_nodes(const float* __restrict__ support,
                                                    const int* __restrict__ counts,
                                                    const int2* __restrict__ buckets,
                                                    const float* __restrict__ bias,
                                                    float* __restrict__ out) {
    __shared__ float4 b4[16];
    if (threadIdx.x < 16) b4[threadIdx.x] = ((const float4*)bias)[threadIdx.x];
    __syncthreads();

    const int node = blockIdx.x * 16 + (threadIdx.x >> 4);
    const int l = threadIdx.x & 15;
    if (node >= N_NODES) return;

    int cnt = counts[node];
    cnt = cnt < CAP ? cnt : CAP;

    float4 acc = b4[l];
    const int2* bk = buckets + (size_t)node * CAP;
    for (int k = 0; k < cnt; ++k) {
        const int2 p = bk[k];                      // broadcast across 16 lanes
        const float w = __int_as_float(p.y);
        const float4 v = ((const float4*)(support + (size_t)p.x * D))[l];
        acc.x += w * v.x;
        acc.y += w * v.y;
        acc.z += w * v.z;
        acc.w += w * v.w;
    }
    ((float4*)out)[(size_t)node * 16 + l] = acc;   // contiguous across block
}

// ---------------------------------------------------------------------------
// Kernel 4: rare overflow edges -> atomic scatter (usually ~0 work)
// ---------------------------------------------------------------------------
__global__ __launch_bounds__(256) void scatter_ovf(const int* __restrict__ ei,
                                                   const float* __restrict__ ew,
                                                   const float* __restrict__ support,
                                                   const int* __restrict__ ovf_cnt,
                                                   const int* __restrict__ ovf_list,
                                                   float* __restrict__ out) {
    const int n = *ovf_cnt;
    for (int i = blockIdx.x * 256 + threadIdx.x; i < n; i += gridDim.x * 256) {
        const int e = ovf_list[i];
        const int src = ei[e];
        const int dst = ei[N_EDGES + e];
        const float w = ew[e];
        const float* s = support + (size_t)src * D;
        float* o = out + (size_t)dst * D;
        for (int j = 0; j < D; ++j) atomicAdd(o + j, w * s[j]);
    }
}

// ---------------------------------------------------------------------------
// Fallback kernels (round-1 atomic path) if ws_size is too small
// ---------------------------------------------------------------------------
__global__ __launch_bounds__(256) void init_out(const float* __restrict__ bias,
                                                float* __restrict__ out) {
    __shared__ float4 b4[16];
    if (threadIdx.x < 16) b4[threadIdx.x] = ((const float4*)bias)[threadIdx.x];
    __syncthreads();
    const int idx = blockIdx.x * 256 + threadIdx.x;
    if (idx < N_NODES * 16) ((float4*)out)[idx] = b4[idx & 15];
}

__global__ __launch_bounds__(256) void scatter_edges(const int* __restrict__ ei,
                                                     const float* __restrict__ ew,
                                                     const float* __restrict__ support,
                                                     float* __restrict__ out) {
    const long tid = (long)blockIdx.x * 256 + threadIdx.x;
    const int e = (int)(tid >> 4);
    const int l = (int)(tid & 15);
    if (e >= N_EDGES) return;
    const int src = ei[e];
    const int dst = ei[N_EDGES + e];
    const float wt = ew[e];
    const float4 v = ((const float4*)(support + (size_t)src * D))[l];
    float* o = out + (size_t)dst * D + l * 4;
    atomicAdd(o + 0, v.x * wt);
    atomicAdd(o + 1, v.y * wt);
    atomicAdd(o + 2, v.z * wt);
    atomicAdd(o + 3, v.w * wt);
}

// ---------------------------------------------------------------------------
extern "C" void kernel_launch(void* const* d_in, const int* in_sizes, int n_in,
                              void* d_out, int out_size, void* d_ws, size_t ws_size,
                              hipStream_t stream) {
    const float* x      = (const float*)d_in[0];
    const int*   ei     = (const int*)d_in[1];
    const float* ew     = (const float*)d_in[2];
    const float* weight = (const float*)d_in[3];
    const float* bias   = (const float*)d_in[4];
    float* out = (float*)d_out;

    char* ws = (char*)d_ws;
    float* support = (float*)(ws + OFF_SUPPORT);

    // 1. support = X @ W
    gemm_xw<<<(N_NODES + 255) / 256, 256, 0, stream>>>(x, weight, support);

    if (ws_size >= (size_t)WS_NEEDED) {
        int*  counts   = (int*)(ws + OFF_COUNTS);
        int*  ovf_cnt  = (int*)(ws + OFF_OVFCNT);
        int2* buckets  = (int2*)(ws + OFF_BUCKETS);
        int*  ovf_list = (int*)(ws + OFF_OVF);

        // 2. zero counts + overflow counter (contiguous region)
        hipMemsetAsync(ws + OFF_COUNTS, 0, CNT_BYTES + OVFCNT_BYTES, stream);

        // 3. bucket edges by dst
        fill_buckets<<<(N_EDGES + 255) / 256, 256, 0, stream>>>(
            ei, ew, counts, buckets, ovf_cnt, ovf_list);

        // 4. out = bias + segment-sum over buckets
        gather_nodes<<<(N_NODES + 15) / 16, 256, 0, stream>>>(
            support, counts, buckets, bias, out);

        // 5. overflow cleanup (tiny)
        scatter_ovf<<<64, 256, 0, stream>>>(ei, ew, support, ovf_cnt, ovf_list, out);
    } else {
        // fallback: atomic scatter path
        init_out<<<(N_NODES * 16 + 255) / 256, 256, 0, stream>>>(bias, out);
        const long total = (long)N_EDGES * 16;
        scatter_edges<<<(int)((total + 255) / 256), 256, 0, stream>>>(ei, ew, support, out);
    }
}

// Round 3
// 153.520 us; speedup vs baseline: 7.3765x; 1.2756x over previous
//
#include <hip/hip_runtime.h>

#define N_NODES 80000
#define N_EDGES 1280000
#define D 64            // D_IN == D_OUT == 64
#define NB 1250         // bins (64 nodes each: 1250*64 = 80000)
#define NPB 64          // nodes per bin
#define NP 8            // sub-partitions (~XCDs) per bin
#define SUBCAP 224      // per (partition,bin) record capacity (Poisson(128)+8.5 sigma)

// ---------------- workspace layout (bytes) ----------------
#define OFF_SUP   0u
#define SUP_BYTES (N_NODES * D * 2u)                 // 10,240,000  (bf16 support)
#define OFF_CNT   (OFF_SUP + SUP_BYTES)
#define CNT_BYTES (NP * NB * 4u)                     //     40,000
#define OFF_OVC   (OFF_CNT + CNT_BYTES)
#define OVC_BYTES 256u
#define OFF_REC   (OFF_OVC + OVC_BYTES)
#define REC_BYTES (NP * NB * SUBCAP * 8u)            // 17,920,000
#define OFF_OVF   (OFF_REC + REC_BYTES)
#define OVF_BYTES (N_EDGES * 4u)                     //  5,120,000
#define WS_NEEDED (OFF_OVF + OVF_BYTES)              // ~33.3 MB

// round-to-nearest-even f32 -> bf16 pair packed in one uint (a=lo, b=hi)
__device__ inline unsigned bf16pair(float a, float b) {
    unsigned ua = __float_as_uint(a);
    unsigned ub = __float_as_uint(b);
    ua = (ua + 0x7fffu + ((ua >> 16) & 1u)) >> 16;
    ub = (ub + 0x7fffu + ((ub >> 16) & 1u)) & 0xffff0000u;
    return ua | ub;
}

// ---------------------------------------------------------------------------
// Kernel 1: support = X @ W  -> bf16   (one thread per row; W staged in LDS)
// ---------------------------------------------------------------------------
__global__ __launch_bounds__(256) void gemm_xw(const float* __restrict__ x,
                                               const float* __restrict__ w,
                                               unsigned* __restrict__ sup) {
    __shared__ float4 Ws[D * 16];
    const int tid = threadIdx.x;
    for (int i = tid; i < D * 16; i += 256) Ws[i] = ((const float4*)w)[i];
    __syncthreads();

    const int row = blockIdx.x * 256 + tid;
    if (row >= N_NODES) return;

    const float4* xr = (const float4*)(x + (size_t)row * D);
    float4 acc[16];
#pragma unroll
    for (int j = 0; j < 16; ++j) acc[j] = make_float4(0.f, 0.f, 0.f, 0.f);

    for (int k4 = 0; k4 < 16; ++k4) {
        const float4 xv = xr[k4];
        const float xs[4] = {xv.x, xv.y, xv.z, xv.w};
#pragma unroll
        for (int kk = 0; kk < 4; ++kk) {
            const float xk = xs[kk];
            const int k = k4 * 4 + kk;
#pragma unroll
            for (int j = 0; j < 16; ++j) {
                const float4 wv = Ws[k * 16 + j];
                acc[j].x += xk * wv.x;
                acc[j].y += xk * wv.y;
                acc[j].z += xk * wv.z;
                acc[j].w += xk * wv.w;
            }
        }
    }

    // pack 64 floats -> 32 uints (bf16 pairs) -> 8 uint4 stores
    unsigned* srow = sup + (size_t)row * 32;
#pragma unroll
    for (int j = 0; j < 8; ++j) {
        uint4 u;
        u.x = bf16pair(acc[2 * j].x,     acc[2 * j].y);
        u.y = bf16pair(acc[2 * j].z,     acc[2 * j].w);
        u.z = bf16pair(acc[2 * j + 1].x, acc[2 * j + 1].y);
        u.w = bf16pair(acc[2 * j + 1].z, acc[2 * j + 1].w);
        ((uint4*)srow)[j] = u;
    }
}

// ---------------------------------------------------------------------------
// Kernel 2: partition edges into (xcd, bin) record streams.
//   bin = dst>>6 ; record = (src | dst_lo<<17, weight)
//   partition p = blockIdx&7 keeps each append stream XCD-local -> L2-coalesced
// ---------------------------------------------------------------------------
__global__ __launch_bounds__(256) void partition_edges(const int* __restrict__ ei,
                                                       const float* __restrict__ ew,
                                                       int* __restrict__ cnt,
                                                       int2* __restrict__ recs,
                                                       int* __restrict__ ovf_cnt,
                                                       int* __restrict__ ovf_list) {
    const int e = blockIdx.x * 256 + threadIdx.x;
    if (e >= N_EDGES) return;
    const int p = blockIdx.x & (NP - 1);
    const int dst = ei[N_EDGES + e];
    const int bin = dst >> 6;
    const int slot = atomicAdd(&cnt[p * NB + bin], 1);
    if (slot < SUBCAP) {
        const int src = ei[e];
        recs[((size_t)(p * NB + bin)) * SUBCAP + slot] =
            make_int2(src | ((dst & 63) << 17), __float_as_int(ew[e]));
    } else {
        const int q = atomicAdd(ovf_cnt, 1);
        ovf_list[q] = e;
    }
}

// ---------------------------------------------------------------------------
// Kernel 3: per-bin LDS CSR build + gather + out write.  1 block per bin.
// ---------------------------------------------------------------------------
__global__ __launch_bounds__(256) void gather_bins(const unsigned* __restrict__ sup,
                                                   const int* __restrict__ cnt,
                                                   const int2* __restrict__ recs,
                                                   const float* __restrict__ bias,
                                                   float* __restrict__ out) {
    __shared__ int2 lrec[NP * SUBCAP];    // 14,336 B
    __shared__ int2 lcsr[NP * SUBCAP];    // 14,336 B
    __shared__ int  scnt[NP], sbase[NP];
    __shared__ int  lcnt[NPB];
    __shared__ int  lcur[NPB];
    __shared__ int  loff[NPB + 1];
    __shared__ int  stotal;
    __shared__ float4 b4[16];

    const int tid = threadIdx.x;
    const int bin = blockIdx.x;

    if (tid < 16) b4[tid] = ((const float4*)bias)[tid];
    if (tid < NP) {
        int c = cnt[tid * NB + bin];
        scnt[tid] = c < SUBCAP ? c : SUBCAP;
    }
    if (tid < NPB) lcnt[tid] = 0;
    __syncthreads();
    if (tid == 0) {
        int run = 0;
#pragma unroll
        for (int p = 0; p < NP; ++p) { sbase[p] = run; run += scnt[p]; }
        stotal = run;
    }
    __syncthreads();

    // stage records into LDS + per-node counts
    for (int p = 0; p < NP; ++p) {
        const int sc = scnt[p];
        const int2* g = recs + ((size_t)(p * NB + bin)) * SUBCAP;
        for (int i = tid; i < sc; i += 256) {
            const int2 r = g[i];
            lrec[sbase[p] + i] = r;
            atomicAdd(&lcnt[(r.x >> 17) & 63], 1);
        }
    }
    __syncthreads();

    // wave 0: exclusive scan over 64 node counts
    if (tid < 64) {
        const int my = lcnt[tid];
        int v = my;
#pragma unroll
        for (int d = 1; d < 64; d <<= 1) {
            const int o = __shfl_up(v, d);
            if (tid >= d) v += o;
        }
        loff[tid + 1] = v;          // inclusive
        lcur[tid] = v - my;         // exclusive (cursor start)
        if (tid == 0) loff[0] = 0;
    }
    __syncthreads();

    // place into CSR
    const int total = stotal;
    for (int i = tid; i < total; i += 256) {
        const int2 r = lrec[i];
        const int pos = atomicAdd(&lcur[(r.x >> 17) & 63], 1);
        lcsr[pos] = r;
    }
    __syncthreads();

    // gather: 16 groups x 16 lanes; 4 nodes per group
    const int g = tid >> 4;
    const int l = tid & 15;
#pragma unroll
    for (int jj = 0; jj < 4; ++jj) {
        const int n = jj * 16 + g;
        const int node = bin * NPB + n;
        float4 acc = b4[l];
        const int kend = loff[n + 1];
        for (int k = loff[n]; k < kend; ++k) {
            const int2 r = lcsr[k];                       // broadcast in group
            const float wt = __int_as_float(r.y);
            const uint2 sv = ((const uint2*)(sup + (size_t)(r.x & 0x1FFFF) * 32))[l];
            acc.x += wt * __uint_as_float(sv.x << 16);
            acc.y += wt * __uint_as_float(sv.x & 0xffff0000u);
            acc.z += wt * __uint_as_float(sv.y << 16);
            acc.w += wt * __uint_as_float(sv.y & 0xffff0000u);
        }
        ((float4*)out)[(size_t)node * 16 + l] = acc;
    }
}

// ---------------------------------------------------------------------------
// Kernel 4: rare overflow edges -> atomic scatter (usually zero work)
// ---------------------------------------------------------------------------
__global__ __launch_bounds__(256) void scatter_ovf(const int* __restrict__ ei,
                                                   const float* __restrict__ ew,
                                                   const unsigned* __restrict__ sup,
                                                   const int* __restrict__ ovf_cnt,
                                                   const int* __restrict__ ovf_list,
                                                   float* __restrict__ out) {
    const int n = *ovf_cnt;
    for (int i = blockIdx.x * 256 + threadIdx.x; i < n; i += gridDim.x * 256) {
        const int e = ovf_list[i];
        const int src = ei[e];
        const int dst = ei[N_EDGES + e];
        const float w = ew[e];
        const unsigned* s = sup + (size_t)src * 32;
        float* o = out + (size_t)dst * D;
        for (int j = 0; j < 32; ++j) {
            const unsigned u = s[j];
            atomicAdd(o + 2 * j,     w * __uint_as_float(u << 16));
            atomicAdd(o + 2 * j + 1, w * __uint_as_float(u & 0xffff0000u));
        }
    }
}

// ---------------------------------------------------------------------------
extern "C" void kernel_launch(void* const* d_in, const int* in_sizes, int n_in,
                              void* d_out, int out_size, void* d_ws, size_t ws_size,
                              hipStream_t stream) {
    const float* x      = (const float*)d_in[0];
    const int*   ei     = (const int*)d_in[1];
    const float* ew     = (const float*)d_in[2];
    const float* weight = (const float*)d_in[3];
    const float* bias   = (const float*)d_in[4];
    float* out = (float*)d_out;

    char* ws = (char*)d_ws;
    unsigned* sup   = (unsigned*)(ws + OFF_SUP);
    int*  cnt       = (int*)(ws + OFF_CNT);
    int*  ovf_cnt   = (int*)(ws + OFF_OVC);
    int2* recs      = (int2*)(ws + OFF_REC);
    int*  ovf_list  = (int*)(ws + OFF_OVF);

    // 1. support = X @ W (bf16)
    gemm_xw<<<(N_NODES + 255) / 256, 256, 0, stream>>>(x, weight, sup);

    // 2. zero bin cursors + overflow counter
    hipMemsetAsync(ws + OFF_CNT, 0, CNT_BYTES + OVC_BYTES, stream);

    // 3. partition edges into XCD-local bin streams
    partition_edges<<<(N_EDGES + 255) / 256, 256, 0, stream>>>(
        ei, ew, cnt, recs, ovf_cnt, ovf_list);

    // 4. per-bin CSR + gather + write out
    gather_bins<<<NB, 256, 0, stream>>>(sup, cnt, recs, bias, out);

    // 5. overflow cleanup (statistically empty, correctness safety net)
    scatter_ovf<<<64, 256, 0, stream>>>(ei, ew, sup, ovf_cnt, ovf_list, out);
}